// Round 1
// baseline (954.231 us; speedup 1.0000x reference)
//
#include <hip/hip_runtime.h>

#define NEG_SLOPE 0.2f

__device__ __forceinline__ float lrelu(float x) { return x >= 0.0f ? x : NEG_SLOPE * x; }

// Fused: 4x4 conv (stride 4 in y, SX in x, zero-pad cols >= W) + lrelu + 1x1 conv + lrelu.
// in: (CIN, H, W) ; out: (16, OH=H/4, OW)
template<int CIN>
__global__ __launch_bounds__(256)
void tile_conv_kernel(const float* __restrict__ in,
                      const float* __restrict__ wa, const float* __restrict__ ba,
                      const float* __restrict__ wb, const float* __restrict__ bb,
                      float* __restrict__ out,
                      int H, int W, int OH, int OW, int SX) {
    // s_wa transposed to [c*16 + ky*4 + kx][co] so inner co-loop is contiguous & broadcast-free
    __shared__ float s_wa[CIN * 256];
    __shared__ float s_wb[256];   // [k][co]
    __shared__ float s_ba[16];
    __shared__ float s_bb[16];
    for (int i = threadIdx.x; i < CIN * 256; i += 256) {
        int co = i & 15, rest = i >> 4;               // rest = c*16 + ky*4 + kx
        s_wa[i] = wa[co * (CIN * 16) + rest];         // wa: (16, CIN, 4, 4)
    }
    if (threadIdx.x < 256) {
        int i = threadIdx.x;
        int co = i & 15, k = i >> 4;
        s_wb[i] = wb[co * 16 + k];                    // wb: (16, 16, 1, 1)
    }
    if (threadIdx.x < 16) {
        s_ba[threadIdx.x] = ba[threadIdx.x];
        s_bb[threadIdx.x] = bb[threadIdx.x];
    }
    __syncthreads();

    int pix = blockIdx.x * 256 + threadIdx.x;
    if (pix >= OH * OW) return;
    int y = pix / OW;
    int x = pix - y * OW;
    int xb = x * SX;

    float m[16];
#pragma unroll
    for (int co = 0; co < 16; co++) m[co] = 0.f;

    for (int c = 0; c < CIN; c++) {
        const float* inp = in + (size_t)(c * H + 4 * y) * W;
#pragma unroll
        for (int ky = 0; ky < 4; ky++) {
#pragma unroll
            for (int kx = 0; kx < 4; kx++) {
                int col = xb + kx;
                float v = (col < W) ? inp[ky * W + col] : 0.f;
                const float* wr = &s_wa[(c * 16 + ky * 4 + kx) * 16];
#pragma unroll
                for (int co = 0; co < 16; co++) m[co] = fmaf(v, wr[co], m[co]);
            }
        }
    }
#pragma unroll
    for (int co = 0; co < 16; co++) m[co] = lrelu(m[co] + s_ba[co]);

    float o[16];
#pragma unroll
    for (int co = 0; co < 16; co++) o[co] = 0.f;
#pragma unroll
    for (int k = 0; k < 16; k++) {
        float v = m[k];
        const float* wr = &s_wb[k * 16];
#pragma unroll
        for (int co = 0; co < 16; co++) o[co] = fmaf(v, wr[co], o[co]);
    }
    int HW = OH * OW;
#pragma unroll
    for (int co = 0; co < 16; co++) out[(size_t)co * HW + pix] = lrelu(o[co] + s_bb[co]);
}

// cv[d, y, j] = sum_c | tl[c,y,j] - (4j-d >= 0 ? tr[c,y,4j-d] : 0) |
__global__ __launch_bounds__(256)
void cost_volume_kernel(const float* __restrict__ tl, const float* __restrict__ tr,
                        float* __restrict__ cv, int h, int w4, int w, int D) {
    int idx = blockIdx.x * 256 + threadIdx.x;
    int total = D * h * w4;
    if (idx >= total) return;
    int j = idx % w4;
    int rest = idx / w4;
    int y = rest % h;
    int d = rest / h;
    int src = 4 * j - d;
    int hw4 = h * w4, hw = h * w;
    float s = 0.f;
    if (src >= 0) {
        const float* tlp = tl + y * w4 + j;
        const float* trp = tr + y * w + src;
#pragma unroll
        for (int c = 0; c < 16; c++)
            s += fabsf(tlp[c * hw4] - trp[c * hw]);
    } else {
        const float* tlp = tl + y * w4 + j;
#pragma unroll
        for (int c = 0; c < 16; c++)
            s += fabsf(tlp[c * hw4]);
    }
    cv[idx] = s;
}

// out channels: [disp, 0, 0, lrelu(dw @ [min_cost; feat] + db) (13)]
__global__ __launch_bounds__(256)
void hyp_kernel(const float* __restrict__ cv, const float* __restrict__ feat,
                const float* __restrict__ dw, const float* __restrict__ db,
                float* __restrict__ out, int h, int w4, int D, int CF) {
    int pix = blockIdx.x * 256 + threadIdx.x;
    int hw = h * w4;
    if (pix >= hw) return;
    float mn = cv[pix];
    int arg = 0;
    for (int d = 1; d < D; d++) {
        float v = cv[(size_t)d * hw + pix];
        if (v < mn) { mn = v; arg = d; }   // strict < : first occurrence, matches jnp.argmin
    }
    float acc[13];
#pragma unroll
    for (int o = 0; o < 13; o++) acc[o] = dw[o * (CF + 1)] * mn;
    for (int c = 0; c < CF; c++) {
        float v = feat[(size_t)c * hw + pix];
#pragma unroll
        for (int o = 0; o < 13; o++) acc[o] = fmaf(v, dw[o * (CF + 1) + 1 + c], acc[o]);
    }
    out[pix] = (float)arg;
    out[hw + pix] = 0.f;
    out[2 * hw + pix] = 0.f;
#pragma unroll
    for (int o = 0; o < 13; o++) out[(size_t)(3 + o) * hw + pix] = lrelu(acc[o] + db[o]);
}

static inline void launch_tile(const float* in, const float* wa, const float* ba,
                               const float* wb, const float* bb, float* out,
                               int C, int H, int W, int OW, int SX, hipStream_t stream) {
    int OH = H / 4;
    int n = OH * OW;
    int blocks = (n + 255) / 256;
    if (C == 32)
        tile_conv_kernel<32><<<blocks, 256, 0, stream>>>(in, wa, ba, wb, bb, out, H, W, OH, OW, SX);
    else if (C == 24)
        tile_conv_kernel<24><<<blocks, 256, 0, stream>>>(in, wa, ba, wb, bb, out, H, W, OH, OW, SX);
    else
        tile_conv_kernel<16><<<blocks, 256, 0, stream>>>(in, wa, ba, wb, bb, out, H, W, OH, OW, SX);
}

extern "C" void kernel_launch(void* const* d_in, const int* in_sizes, int n_in,
                              void* d_out, int out_size, void* d_ws, size_t ws_size,
                              hipStream_t stream) {
    (void)in_sizes; (void)n_in; (void)out_size; (void)ws_size;
    float* out = (float*)d_out;
    float* ws = (float*)d_ws;

    // Level order: s = 16, 8, 4, 2, 1  (index 0..4)
    const int C[5] = {32, 24, 24, 16, 16};
    const int H[5] = {24, 48, 96, 192, 384};
    const int W[5] = {80, 160, 320, 640, 1280};
    const int D[5] = {20, 40, 80, 160, 320};
    const int wa_i[5] = {10, 14, 18, 22, 26};
    const int dw_i[5] = {30, 32, 34, 36, 38};

    // d_out offsets (floats): cv16,cv8,cv4,cv2,cv1,hyp16,hyp8,hyp4,hyp2,hyp1
    const size_t cv_off[5]  = {0, 2400, 21600, 175200, 1404000};
    const size_t hyp_off[5] = {11234400, 11236320, 11244000, 11274720, 11397600};

    // d_ws offsets (floats)
    const size_t tl_off[5] = {0, 9600, 48000, 201600, 816000};
    const size_t tr_off[5] = {1920, 17280, 78720, 324480, 1307520};

    const float* fl[5] = {(const float*)d_in[0], (const float*)d_in[1], (const float*)d_in[2],
                          (const float*)d_in[3], (const float*)d_in[4]};
    const float* fr[5] = {(const float*)d_in[5], (const float*)d_in[6], (const float*)d_in[7],
                          (const float*)d_in[8], (const float*)d_in[9]};

    // 1) tile features (tl: stride 4,4 ; tr: stride 4,1 with right-pad 3)
    for (int l = 0; l < 5; l++) {
        const float* wa = (const float*)d_in[wa_i[l]];
        const float* ba = (const float*)d_in[wa_i[l] + 1];
        const float* wb = (const float*)d_in[wa_i[l] + 2];
        const float* bb = (const float*)d_in[wa_i[l] + 3];
        launch_tile(fl[l], wa, ba, wb, bb, ws + tl_off[l], C[l], H[l], W[l], W[l] / 4, 4, stream);
        launch_tile(fr[l], wa, ba, wb, bb, ws + tr_off[l], C[l], H[l], W[l], W[l],     1, stream);
    }

    // 2) cost volumes -> d_out directly
    for (int l = 0; l < 5; l++) {
        int h = H[l] / 4, w4 = W[l] / 4, w = W[l];
        int total = D[l] * h * w4;
        int blocks = (total + 255) / 256;
        cost_volume_kernel<<<blocks, 256, 0, stream>>>(ws + tl_off[l], ws + tr_off[l],
                                                       out + cv_off[l], h, w4, w, D[l]);
    }

    // 3) hyp heads. feats: tl16, tl8, fea_l16, fea_l8, fea_l4
    const float* feat[5] = {ws + tl_off[0], ws + tl_off[1], fl[0], fl[1], fl[2]};
    const int   CF[5]    = {16, 16, 32, 24, 24};
    for (int l = 0; l < 5; l++) {
        int h = H[l] / 4, w4 = W[l] / 4;
        int hw = h * w4;
        int blocks = (hw + 255) / 256;
        hyp_kernel<<<blocks, 256, 0, stream>>>(out + cv_off[l], feat[l],
                                               (const float*)d_in[dw_i[l]],
                                               (const float*)d_in[dw_i[l] + 1],
                                               out + hyp_off[l], h, w4, D[l], CF[l]);
    }
}

// Round 2
// 814.453 us; speedup vs baseline: 1.1716x; 1.1716x over previous
//
#include <hip/hip_runtime.h>
#include <float.h>

#define NEG_SLOPE 0.2f

__device__ __forceinline__ float lrelu(float x) { return x >= 0.0f ? x : NEG_SLOPE * x; }

// ---------------- tile conv LEFT: stride (4,4), aligned float4 loads ----------------
// in: (CIN,H,W) -> out: (16, H/4, W/4)
template<int CIN>
__global__ __launch_bounds__(256)
void tile_conv_l(const float* __restrict__ in,
                 const float* __restrict__ wa, const float* __restrict__ ba,
                 const float* __restrict__ wb, const float* __restrict__ bb,
                 float* __restrict__ out, int H, int W, int OH, int OW) {
    __shared__ float s_wa[CIN * 256];   // [c*16 + r*4 + kx][co]
    __shared__ float s_wb[256];         // [k][co]
    __shared__ float s_ba[16], s_bb[16];
    for (int i = threadIdx.x; i < CIN * 256; i += 256) {
        int co = i & 15, rest = i >> 4;
        s_wa[i] = wa[co * (CIN * 16) + rest];
    }
    {
        int i = threadIdx.x;
        s_wb[i] = wb[(i & 15) * 16 + (i >> 4)];
        if (i < 16) { s_ba[i] = ba[i]; s_bb[i] = bb[i]; }
    }
    __syncthreads();

    int pix = blockIdx.x * 256 + threadIdx.x;
    if (pix >= OH * OW) return;
    int y = pix / OW, x = pix - y * OW;

    float m[16];
#pragma unroll
    for (int co = 0; co < 16; co++) m[co] = 0.f;

    for (int c = 0; c < CIN; c++) {
        const float* rowb = in + (size_t)(c * H + 4 * y) * W + 4 * x;
#pragma unroll
        for (int r = 0; r < 4; r++) {
            float4 v = *(const float4*)(rowb + r * W);
            const float* wr = &s_wa[(c * 16 + r * 4) * 16];
#pragma unroll
            for (int co = 0; co < 16; co++) m[co] = fmaf(v.x, wr[co], m[co]);
#pragma unroll
            for (int co = 0; co < 16; co++) m[co] = fmaf(v.y, wr[16 + co], m[co]);
#pragma unroll
            for (int co = 0; co < 16; co++) m[co] = fmaf(v.z, wr[32 + co], m[co]);
#pragma unroll
            for (int co = 0; co < 16; co++) m[co] = fmaf(v.w, wr[48 + co], m[co]);
        }
    }
#pragma unroll
    for (int co = 0; co < 16; co++) m[co] = lrelu(m[co] + s_ba[co]);

    float o[16];
#pragma unroll
    for (int co = 0; co < 16; co++) o[co] = 0.f;
#pragma unroll
    for (int k = 0; k < 16; k++) {
        float v = m[k];
        const float* wr = &s_wb[k * 16];
#pragma unroll
        for (int co = 0; co < 16; co++) o[co] = fmaf(v, wr[co], o[co]);
    }
    int HW = OH * OW;
#pragma unroll
    for (int co = 0; co < 16; co++) out[(size_t)co * HW + pix] = lrelu(o[co] + s_bb[co]);
}

// ---------------- tile conv RIGHT: stride (4,1), right-pad 3; 4 outputs/thread ----------------
// in: (CIN,H,W) -> out: (16, H/4, W)
template<int CIN>
__global__ __launch_bounds__(256)
void tile_conv_r(const float* __restrict__ in,
                 const float* __restrict__ wa, const float* __restrict__ ba,
                 const float* __restrict__ wb, const float* __restrict__ bb,
                 float* __restrict__ out, int H, int W, int OH) {
    __shared__ float s_wa[CIN * 256];
    __shared__ float s_wb[256];
    __shared__ float s_ba[16], s_bb[16];
    for (int i = threadIdx.x; i < CIN * 256; i += 256) {
        int co = i & 15, rest = i >> 4;
        s_wa[i] = wa[co * (CIN * 16) + rest];
    }
    {
        int i = threadIdx.x;
        s_wb[i] = wb[(i & 15) * 16 + (i >> 4)];
        if (i < 16) { s_ba[i] = ba[i]; s_bb[i] = bb[i]; }
    }
    __syncthreads();

    int W4 = W >> 2;
    int t = blockIdx.x * 256 + threadIdx.x;
    if (t >= OH * W4) return;
    int y = t / W4, x4 = (t - y * W4) * 4;

    float m[4][16];
#pragma unroll
    for (int i = 0; i < 4; i++)
#pragma unroll
        for (int co = 0; co < 16; co++) m[i][co] = 0.f;

    bool has1 = (x4 + 4) < W;   // last group: cols W..W+3 are all zero-pad
    for (int c = 0; c < CIN; c++) {
#pragma unroll
        for (int r = 0; r < 4; r++) {
            const float* rowb = in + (size_t)(c * H + 4 * y + r) * W + x4;
            float4 f0 = *(const float4*)rowb;
            float4 f1 = make_float4(0.f, 0.f, 0.f, 0.f);
            if (has1) f1 = *(const float4*)(rowb + 4);
            float wv[8] = {f0.x, f0.y, f0.z, f0.w, f1.x, f1.y, f1.z, f1.w};
            const float* wbase = &s_wa[(c * 16 + r * 4) * 16];
#pragma unroll
            for (int i = 0; i < 4; i++) {
#pragma unroll
                for (int kx = 0; kx < 4; kx++) {
                    float v = wv[i + kx];
                    const float* wr = wbase + kx * 16;
#pragma unroll
                    for (int co = 0; co < 16; co++) m[i][co] = fmaf(v, wr[co], m[i][co]);
                }
            }
        }
    }

    int HW = OH * W;
#pragma unroll
    for (int i = 0; i < 4; i++) {
        float mm[16];
#pragma unroll
        for (int co = 0; co < 16; co++) mm[co] = lrelu(m[i][co] + s_ba[co]);
        float o[16];
#pragma unroll
        for (int co = 0; co < 16; co++) o[co] = 0.f;
#pragma unroll
        for (int k = 0; k < 16; k++) {
            float v = mm[k];
            const float* wr = &s_wb[k * 16];
#pragma unroll
            for (int co = 0; co < 16; co++) o[co] = fmaf(v, wr[co], o[co]);
        }
        size_t base = (size_t)y * W + x4 + i;
#pragma unroll
        for (int co = 0; co < 16; co++) out[(size_t)co * HW + base] = lrelu(o[co] + s_bb[co]);
    }
}

// ---------- fused cost volume + min/argmin + hyp head ----------
// block: 64 pixels x 4 d-chunks. Each thread: 4 consecutive d per step via two aligned
// float4 tr loads/channel (b = 4j - d0 is a multiple of 4). Chunks cover ascending,
// contiguous d ranges; strict < everywhere => first-occurrence argmin like jnp.argmin.
__global__ __launch_bounds__(256)
void cost_volume_hyp(const float* __restrict__ tl, const float* __restrict__ tr,
                     const float* __restrict__ feat, const float* __restrict__ dw,
                     const float* __restrict__ db,
                     float* __restrict__ cv, float* __restrict__ hyp,
                     int h, int w4, int w, int D, int gpc, int CF) {
    __shared__ float smin[256];
    __shared__ int sarg[256];
    int npix = h * w4;
    int p = threadIdx.x & 63, chunk = threadIdx.x >> 6;
    int pix = blockIdx.x * 64 + p;
    bool valid = pix < npix;

    float mloc = FLT_MAX; int aloc = 0;
    if (valid) {
        int y = pix / w4, j = pix - y * w4;
        float tlv[16]; float sumabs = 0.f;
#pragma unroll
        for (int c = 0; c < 16; c++) { tlv[c] = tl[(size_t)c * npix + pix]; sumabs += fabsf(tlv[c]); }

        int ngroups = D >> 2;
        int g0 = chunk * gpc;
        int g1 = min(ngroups, g0 + gpc);
        const float* trrow = tr + (size_t)y * w;
        int hw = h * w;
        for (int g = g0; g < g1; g++) {
            int d0 = g << 2;
            int b = 4 * j - d0;
            float a0, a1, a2, a3;
            if (b >= 4) {
                a0 = a1 = a2 = a3 = 0.f;
#pragma unroll
                for (int c = 0; c < 16; c++) {
                    const float* pc = trrow + (size_t)c * hw + b;
                    float4 f0 = *(const float4*)(pc - 4);   // cols b-4..b-1
                    float4 f1 = *(const float4*)(pc);       // cols b..b+3
                    float tv = tlv[c];
                    a0 += fabsf(tv - f1.x);
                    a1 += fabsf(tv - f0.w);
                    a2 += fabsf(tv - f0.z);
                    a3 += fabsf(tv - f0.y);
                }
            } else if (b == 0) {
                a0 = 0.f; a1 = a2 = a3 = sumabs;
#pragma unroll
                for (int c = 0; c < 16; c++) a0 += fabsf(tlv[c] - trrow[(size_t)c * hw]);
            } else {
                a0 = a1 = a2 = a3 = sumabs;
            }
            float* cvp = cv + (size_t)d0 * npix + pix;
            cvp[0] = a0; cvp[npix] = a1; cvp[2 * (size_t)npix] = a2; cvp[3 * (size_t)npix] = a3;
            if (a0 < mloc) { mloc = a0; aloc = d0; }
            if (a1 < mloc) { mloc = a1; aloc = d0 + 1; }
            if (a2 < mloc) { mloc = a2; aloc = d0 + 2; }
            if (a3 < mloc) { mloc = a3; aloc = d0 + 3; }
        }
    }
    smin[threadIdx.x] = mloc;
    sarg[threadIdx.x] = aloc;
    __syncthreads();

    if (threadIdx.x < 64 && valid) {
        float mn = smin[threadIdx.x]; int arg = sarg[threadIdx.x];
#pragma unroll
        for (int c2 = 1; c2 < 4; c2++) {
            float v = smin[c2 * 64 + threadIdx.x];
            if (v < mn) { mn = v; arg = sarg[c2 * 64 + threadIdx.x]; }
        }
        float acc[13];
#pragma unroll
        for (int o = 0; o < 13; o++) acc[o] = dw[o * (CF + 1)] * mn;
        for (int c = 0; c < CF; c++) {
            float v = feat[(size_t)c * npix + pix];
#pragma unroll
            for (int o = 0; o < 13; o++) acc[o] = fmaf(v, dw[o * (CF + 1) + 1 + c], acc[o]);
        }
        hyp[pix] = (float)arg;
        hyp[npix + pix] = 0.f;
        hyp[2 * (size_t)npix + pix] = 0.f;
#pragma unroll
        for (int o = 0; o < 13; o++) hyp[(size_t)(3 + o) * npix + pix] = lrelu(acc[o] + db[o]);
    }
}

// ---------------- launchers ----------------
static inline void launch_l(const float* in, const float* wa, const float* ba,
                            const float* wb, const float* bb, float* out,
                            int C, int H, int W, hipStream_t s) {
    int OH = H / 4, OW = W / 4, n = OH * OW, blocks = (n + 255) / 256;
    if (C == 32)      tile_conv_l<32><<<blocks, 256, 0, s>>>(in, wa, ba, wb, bb, out, H, W, OH, OW);
    else if (C == 24) tile_conv_l<24><<<blocks, 256, 0, s>>>(in, wa, ba, wb, bb, out, H, W, OH, OW);
    else              tile_conv_l<16><<<blocks, 256, 0, s>>>(in, wa, ba, wb, bb, out, H, W, OH, OW);
}
static inline void launch_r(const float* in, const float* wa, const float* ba,
                            const float* wb, const float* bb, float* out,
                            int C, int H, int W, hipStream_t s) {
    int OH = H / 4, n = OH * (W / 4), blocks = (n + 255) / 256;
    if (C == 32)      tile_conv_r<32><<<blocks, 256, 0, s>>>(in, wa, ba, wb, bb, out, H, W, OH);
    else if (C == 24) tile_conv_r<24><<<blocks, 256, 0, s>>>(in, wa, ba, wb, bb, out, H, W, OH);
    else              tile_conv_r<16><<<blocks, 256, 0, s>>>(in, wa, ba, wb, bb, out, H, W, OH);
}

extern "C" void kernel_launch(void* const* d_in, const int* in_sizes, int n_in,
                              void* d_out, int out_size, void* d_ws, size_t ws_size,
                              hipStream_t stream) {
    (void)in_sizes; (void)n_in; (void)out_size; (void)ws_size;
    float* out = (float*)d_out;
    float* ws = (float*)d_ws;

    const int C[5] = {32, 24, 24, 16, 16};
    const int H[5] = {24, 48, 96, 192, 384};
    const int W[5] = {80, 160, 320, 640, 1280};
    const int D[5] = {20, 40, 80, 160, 320};
    const int wa_i[5] = {10, 14, 18, 22, 26};
    const int dw_i[5] = {30, 32, 34, 36, 38};

    const size_t cv_off[5]  = {0, 2400, 21600, 175200, 1404000};
    const size_t hyp_off[5] = {11234400, 11236320, 11244000, 11274720, 11397600};
    const size_t tl_off[5] = {0, 9600, 48000, 201600, 816000};
    const size_t tr_off[5] = {1920, 17280, 78720, 324480, 1307520};
    // min/arg scratch after tl/tr (ends at 3,273,600 floats)
    const size_t mn_base = 3273600; // (unused placeholder kept for layout clarity)
    (void)mn_base;

    const float* fl[5] = {(const float*)d_in[0], (const float*)d_in[1], (const float*)d_in[2],
                          (const float*)d_in[3], (const float*)d_in[4]};
    const float* fr[5] = {(const float*)d_in[5], (const float*)d_in[6], (const float*)d_in[7],
                          (const float*)d_in[8], (const float*)d_in[9]};

    // 1) tile features
    for (int l = 0; l < 5; l++) {
        const float* wa = (const float*)d_in[wa_i[l]];
        const float* ba = (const float*)d_in[wa_i[l] + 1];
        const float* wb = (const float*)d_in[wa_i[l] + 2];
        const float* bb = (const float*)d_in[wa_i[l] + 3];
        launch_l(fl[l], wa, ba, wb, bb, ws + tl_off[l], C[l], H[l], W[l], stream);
        launch_r(fr[l], wa, ba, wb, bb, ws + tr_off[l], C[l], H[l], W[l], stream);
    }

    // 2) fused cost volume + argmin + hyp head
    const float* feat[5] = {ws + tl_off[0], ws + tl_off[1], fl[0], fl[1], fl[2]};
    const int   CF[5]    = {16, 16, 32, 24, 24};
    for (int l = 0; l < 5; l++) {
        int h = H[l] / 4, w4 = W[l] / 4, w = W[l];
        int npix = h * w4;
        int blocks = (npix + 63) / 64;
        int ngroups = D[l] / 4;
        int gpc = (ngroups + 3) / 4;
        cost_volume_hyp<<<blocks, 256, 0, stream>>>(ws + tl_off[l], ws + tr_off[l],
                                                    feat[l],
                                                    (const float*)d_in[dw_i[l]],
                                                    (const float*)d_in[dw_i[l] + 1],
                                                    out + cv_off[l], out + hyp_off[l],
                                                    h, w4, w, D[l], gpc, CF[l]);
    }
}

// Round 3
// 354.225 us; speedup vs baseline: 2.6939x; 2.2993x over previous
//
#include <hip/hip_runtime.h>
#include <float.h>

#define NEG_SLOPE 0.2f

__device__ __forceinline__ float lrelu(float x) { return x >= 0.0f ? x : NEG_SLOPE * x; }

// ============ über tile-conv: all 10 convs (5 levels x {left,right}) in one launch ============
// Block = 64 pixels x 4 channel-chunks. Each chunk accumulates CIN/4 input channels of the
// 4x4 conv into a 16-channel partial, LDS-reduced, lrelu, then 1x1 conv (4 co per thread).
struct ConvSeg {
    const float* in; const float* wa; const float* ba; const float* wb; const float* bb;
    float* out;
    int CIN, H, W, SX, OW, npix, blk0;
};
struct ConvTab { ConvSeg seg[10]; };

__global__ __launch_bounds__(256)
void conv_uber(ConvTab tab) {
    __shared__ float s_wa[32 * 256];      // [c*16 + r*4 + kx][co]
    __shared__ float s_wb[256];           // [k][co]
    __shared__ float s_ba[16], s_bb[16];
    __shared__ float s_part[16 * 256];    // co*256 + tid   (conflict-free: lane stride 1)
    __shared__ float s_m[16 * 64];        // k*64 + p

    int si = 0;
#pragma unroll
    for (int i = 1; i < 10; i++) if ((int)blockIdx.x >= tab.seg[i].blk0) si = i;
    const ConvSeg sg = tab.seg[si];
    const int CIN = sg.CIN;

    for (int i = threadIdx.x; i < CIN * 256; i += 256)
        s_wa[i] = sg.wa[(i & 15) * (CIN * 16) + (i >> 4)];
    {
        int i = threadIdx.x;
        s_wb[i] = sg.wb[(i & 15) * 16 + (i >> 4)];
        if (i < 16) { s_ba[i] = sg.ba[i]; s_bb[i] = sg.bb[i]; }
    }
    __syncthreads();

    const int p = threadIdx.x & 63, chunk = threadIdx.x >> 6;
    const int pix = ((int)blockIdx.x - sg.blk0) * 64 + p;
    const bool valid = pix < sg.npix;

    float m[16];
#pragma unroll
    for (int co = 0; co < 16; co++) m[co] = 0.f;

    const int cpc = CIN >> 2;           // 32->8, 24->6, 16->4
    if (valid) {
        int y = pix / sg.OW, x = pix - y * sg.OW;
        int c0 = chunk * cpc;
        if (sg.SX == 4) {               // left conv: aligned float4 input loads
            for (int c = c0; c < c0 + cpc; c++) {
                const float* rb = sg.in + ((size_t)(c * sg.H + 4 * y)) * sg.W + 4 * x;
                const float* wc = &s_wa[c * 256];
#pragma unroll
                for (int r = 0; r < 4; r++) {
                    float4 v = *(const float4*)(rb + r * sg.W);
                    const float* wr = wc + r * 64;
#pragma unroll
                    for (int co = 0; co < 16; co++) m[co] = fmaf(v.x, wr[co], m[co]);
#pragma unroll
                    for (int co = 0; co < 16; co++) m[co] = fmaf(v.y, wr[16 + co], m[co]);
#pragma unroll
                    for (int co = 0; co < 16; co++) m[co] = fmaf(v.z, wr[32 + co], m[co]);
#pragma unroll
                    for (int co = 0; co < 16; co++) m[co] = fmaf(v.w, wr[48 + co], m[co]);
                }
            }
        } else {                        // right conv: stride-1 cols x..x+3, zero-pad >= W
            for (int c = c0; c < c0 + cpc; c++) {
                const float* wc = &s_wa[c * 256];
#pragma unroll
                for (int r = 0; r < 4; r++) {
                    const float* rb = sg.in + ((size_t)(c * sg.H + 4 * y + r)) * sg.W;
                    const float* wr = wc + r * 64;
#pragma unroll
                    for (int kx = 0; kx < 4; kx++) {
                        int col = x + kx;
                        float v = (col < sg.W) ? rb[col] : 0.f;
                        const float* w2 = wr + kx * 16;
#pragma unroll
                        for (int co = 0; co < 16; co++) m[co] = fmaf(v, w2[co], m[co]);
                    }
                }
            }
        }
    }
#pragma unroll
    for (int co = 0; co < 16; co++) s_part[co * 256 + threadIdx.x] = m[co];
    __syncthreads();

    // reduce 4 chunks, bias+lrelu; thread (p,chunk) owns co = chunk*4..chunk*4+3
#pragma unroll
    for (int i = 0; i < 4; i++) {
        int co = chunk * 4 + i;
        float v = s_part[co * 256 + p] + s_part[co * 256 + 64 + p]
                + s_part[co * 256 + 128 + p] + s_part[co * 256 + 192 + p];
        s_m[co * 64 + p] = lrelu(v + s_ba[co]);
    }
    __syncthreads();

    float o[4] = {0.f, 0.f, 0.f, 0.f};
#pragma unroll
    for (int k = 0; k < 16; k++) {
        float mk = s_m[k * 64 + p];
        const float* wr = &s_wb[k * 16 + chunk * 4];
#pragma unroll
        for (int i = 0; i < 4; i++) o[i] = fmaf(mk, wr[i], o[i]);
    }
    if (valid) {
#pragma unroll
        for (int i = 0; i < 4; i++) {
            int co = chunk * 4 + i;
            sg.out[(size_t)co * sg.npix + pix] = lrelu(o[i] + s_bb[co]);
        }
    }
}

// ============ über cost-volume + argmin + hyp head: all 5 levels in one launch ============
struct CvSeg {
    const float* tl; const float* tr; const float* feat;
    const float* dw; const float* db;
    float* cv; float* hyp;
    int h, w4, w, D, gpc, CF, blk0;
};
struct CvTab { CvSeg seg[5]; };

__global__ __launch_bounds__(256)
void cv_hyp_uber(CvTab tab) {
    __shared__ float smin[256];
    __shared__ int sarg[256];

    int si = 0;
#pragma unroll
    for (int i = 1; i < 5; i++) if ((int)blockIdx.x >= tab.seg[i].blk0) si = i;
    const CvSeg sg = tab.seg[si];

    const int npix = sg.h * sg.w4;
    const int p = threadIdx.x & 63, chunk = threadIdx.x >> 6;
    const int pix = ((int)blockIdx.x - sg.blk0) * 64 + p;
    const bool valid = pix < npix;

    float mloc = FLT_MAX; int aloc = 0;
    if (valid) {
        int y = pix / sg.w4, j = pix - y * sg.w4;
        float tlv[16]; float sumabs = 0.f;
#pragma unroll
        for (int c = 0; c < 16; c++) { tlv[c] = sg.tl[(size_t)c * npix + pix]; sumabs += fabsf(tlv[c]); }

        int ngroups = sg.D >> 2;
        int g0 = chunk * sg.gpc;
        int g1 = min(ngroups, g0 + sg.gpc);
        const float* trrow = sg.tr + (size_t)y * sg.w;
        int hw = sg.h * sg.w;

        // carry[c] invariant: entering group g, carry[c] == tr[c][b_g] (b_g = 4j-4g), when b_g >= 0
        float carry[16];
        int b0 = 4 * j - 4 * g0;
        if (g0 < g1 && b0 >= 0) {
#pragma unroll
            for (int c = 0; c < 16; c++) carry[c] = trrow[(size_t)c * hw + b0];
        }
        for (int g = g0; g < g1; g++) {
            int b = 4 * j - 4 * g;
            float a0, a1, a2, a3;
            if (b >= 4) {
                a0 = a1 = a2 = a3 = 0.f;
#pragma unroll
                for (int c = 0; c < 16; c++) {
                    float4 f0 = *(const float4*)(trrow + (size_t)c * hw + (b - 4));  // cols b-4..b-1
                    float tv = tlv[c];
                    a0 += fabsf(tv - carry[c]);    // tr[b]
                    a1 += fabsf(tv - f0.w);        // tr[b-1]
                    a2 += fabsf(tv - f0.z);        // tr[b-2]
                    a3 += fabsf(tv - f0.y);        // tr[b-3]
                    carry[c] = f0.x;               // tr[b-4] for next group
                }
            } else if (b == 0) {
                a0 = 0.f; a1 = a2 = a3 = sumabs;
#pragma unroll
                for (int c = 0; c < 16; c++) a0 += fabsf(tlv[c] - carry[c]);
            } else {
                a0 = a1 = a2 = a3 = sumabs;
            }
            float* cvp = sg.cv + (size_t)(4 * g) * npix + pix;
            cvp[0] = a0; cvp[npix] = a1; cvp[2 * (size_t)npix] = a2; cvp[3 * (size_t)npix] = a3;
            if (a0 < mloc) { mloc = a0; aloc = 4 * g; }
            if (a1 < mloc) { mloc = a1; aloc = 4 * g + 1; }
            if (a2 < mloc) { mloc = a2; aloc = 4 * g + 2; }
            if (a3 < mloc) { mloc = a3; aloc = 4 * g + 3; }
        }
    }
    smin[threadIdx.x] = mloc;
    sarg[threadIdx.x] = aloc;
    __syncthreads();

    if (threadIdx.x < 64 && valid) {
        float mn = smin[threadIdx.x]; int arg = sarg[threadIdx.x];
#pragma unroll
        for (int c2 = 1; c2 < 4; c2++) {
            float v = smin[c2 * 64 + threadIdx.x];
            if (v < mn) { mn = v; arg = sarg[c2 * 64 + threadIdx.x]; }
        }
        float acc[13];
#pragma unroll
        for (int o = 0; o < 13; o++) acc[o] = sg.dw[o * (sg.CF + 1)] * mn;
        for (int c = 0; c < sg.CF; c++) {
            float v = sg.feat[(size_t)c * npix + pix];
#pragma unroll
            for (int o = 0; o < 13; o++) acc[o] = fmaf(v, sg.dw[o * (sg.CF + 1) + 1 + c], acc[o]);
        }
        sg.hyp[pix] = (float)arg;
        sg.hyp[npix + pix] = 0.f;
        sg.hyp[2 * (size_t)npix + pix] = 0.f;
#pragma unroll
        for (int o = 0; o < 13; o++) sg.hyp[(size_t)(3 + o) * npix + pix] = lrelu(acc[o] + sg.db[o]);
    }
}

extern "C" void kernel_launch(void* const* d_in, const int* in_sizes, int n_in,
                              void* d_out, int out_size, void* d_ws, size_t ws_size,
                              hipStream_t stream) {
    (void)in_sizes; (void)n_in; (void)out_size; (void)ws_size;
    float* out = (float*)d_out;
    float* ws = (float*)d_ws;

    const int C[5] = {32, 24, 24, 16, 16};
    const int H[5] = {24, 48, 96, 192, 384};
    const int W[5] = {80, 160, 320, 640, 1280};
    const int D[5] = {20, 40, 80, 160, 320};
    const int wa_i[5] = {10, 14, 18, 22, 26};
    const int dw_i[5] = {30, 32, 34, 36, 38};

    const size_t cv_off[5]  = {0, 2400, 21600, 175200, 1404000};
    const size_t hyp_off[5] = {11234400, 11236320, 11244000, 11274720, 11397600};
    const size_t tl_off[5] = {0, 9600, 48000, 201600, 816000};
    const size_t tr_off[5] = {1920, 17280, 78720, 324480, 1307520};

    const float* fl[5] = {(const float*)d_in[0], (const float*)d_in[1], (const float*)d_in[2],
                          (const float*)d_in[3], (const float*)d_in[4]};
    const float* fr[5] = {(const float*)d_in[5], (const float*)d_in[6], (const float*)d_in[7],
                          (const float*)d_in[8], (const float*)d_in[9]};

    // ---- build conv table: biggest segments first for load balance ----
    // order: r1, l1, r2, l2, r4, l4, r8, l8, r16, l16  (level index l, side: r=right SX=1, l=left SX=4)
    const int ord_lvl[10]  = {4, 4, 3, 3, 2, 2, 1, 1, 0, 0};
    const int ord_side[10] = {1, 0, 1, 0, 1, 0, 1, 0, 1, 0};   // 1 = right
    ConvTab ct;
    int blk = 0;
    for (int i = 0; i < 10; i++) {
        int l = ord_lvl[i]; bool right = ord_side[i];
        ConvSeg& s = ct.seg[i];
        s.in = right ? fr[l] : fl[l];
        s.wa = (const float*)d_in[wa_i[l]];
        s.ba = (const float*)d_in[wa_i[l] + 1];
        s.wb = (const float*)d_in[wa_i[l] + 2];
        s.bb = (const float*)d_in[wa_i[l] + 3];
        s.out = ws + (right ? tr_off[l] : tl_off[l]);
        s.CIN = C[l]; s.H = H[l]; s.W = W[l];
        s.SX = right ? 1 : 4;
        s.OW = right ? W[l] : W[l] / 4;
        s.npix = (H[l] / 4) * s.OW;
        s.blk0 = blk;
        blk += (s.npix + 63) / 64;
    }
    conv_uber<<<blk, 256, 0, stream>>>(ct);

    // ---- build cv table: level 1 (biggest) first ----
    const float* feat[5] = {ws + tl_off[0], ws + tl_off[1], fl[0], fl[1], fl[2]};
    const int   CF[5]    = {16, 16, 32, 24, 24};
    CvTab vt;
    blk = 0;
    for (int i = 0; i < 5; i++) {
        int l = 4 - i;
        CvSeg& s = vt.seg[i];
        s.tl = ws + tl_off[l]; s.tr = ws + tr_off[l];
        s.feat = feat[l];
        s.dw = (const float*)d_in[dw_i[l]];
        s.db = (const float*)d_in[dw_i[l] + 1];
        s.cv = out + cv_off[l]; s.hyp = out + hyp_off[l];
        s.h = H[l] / 4; s.w4 = W[l] / 4; s.w = W[l]; s.D = D[l];
        int ngroups = D[l] / 4;
        s.gpc = (ngroups + 3) / 4;
        s.CF = CF[l];
        s.blk0 = blk;
        blk += (s.h * s.w4 + 63) / 64;
    }
    cv_hyp_uber<<<blk, 256, 0, stream>>>(vt);
}